// Round 1
// baseline (2574.249 us; speedup 1.0000x reference)
//
#include <hip/hip_runtime.h>

typedef unsigned short u16;
typedef unsigned int u32;
typedef unsigned long long u64;
typedef __attribute__((ext_vector_type(8))) short short8;
typedef __attribute__((ext_vector_type(4))) float f32x4;
typedef __attribute__((ext_vector_type(4))) u32 u32x4;

#define H_ 1024
#define G4_ 4096
#define T_ 256
#define B_ 32
#define RN_ 8388608  // B*T*H
#define MFMA16(a, b, c) __builtin_amdgcn_mfma_f32_16x16x32_bf16(a, b, c, 0, 0, 0)

__device__ __forceinline__ u16 f2bf(float f) {
  union { float f; u32 u; } v; v.f = f;
  u32 r = v.u + 0x7fffu + ((v.u >> 16) & 1u);  // RNE (inputs finite)
  return (u16)(r >> 16);
}
__device__ __forceinline__ float bf2f(u16 h) {
  union { u32 u; float f; } v; v.u = ((u32)h) << 16;
  return v.f;
}
__device__ __forceinline__ u32 pk2(float a, float b) {
  return (u32)f2bf(a) | ((u32)f2bf(b) << 16);
}
// scan column ordering: R = blk*32 + u_local*4 + gate  ->  original g = gate*1024 + blk*8 + u_local
__device__ __forceinline__ int permcol(int R) {
  return (R & 3) * 1024 + ((R >> 5) << 3) + ((R >> 2) & 7);
}
__device__ __forceinline__ float sigm(float x) { return 1.f / (1.f + __expf(-x)); }
__device__ __forceinline__ float tanh_(float x) {
  float e = __expf(2.f * x);
  return 1.f - 2.f / (e + 1.f);  // saturates correctly at +-1
}

// -------- transpose + convert + permute: out[R][k] = bf16( in[k][permcol(R)] ) --------
__global__ __launch_bounds__(256) void transpose_convert(
    const float* __restrict__ Wx, const float* __restrict__ Wh,
    u16* __restrict__ WxT, u16* __restrict__ WhT) {
  __shared__ float lds[64][65];
  const int bid = blockIdx.x, tid = threadIdx.x;
  const int sel = bid >> 10;             // 0,1: Wx l0,l1 ; 2,3: Wh l0,l1
  const int tile = bid & 1023;
  const int kt = tile & 15, rt = tile >> 4;   // 16 k-tiles x 64 R-tiles
  const float* src = (sel < 2 ? Wx : Wh) + (size_t)(sel & 1) * ((size_t)H_ * G4_);
  u16* dst = (sel < 2 ? WxT : WhT) + (size_t)(sel & 1) * ((size_t)G4_ * H_);
#pragma unroll
  for (int ii = 0; ii < 16; ++ii) {
    int idx = ii * 256 + tid;
    int r = idx >> 6, c = idx & 63;
    int run = c >> 3, u = c & 7;
    int blkLoc = run >> 2, gate = run & 3;
    int g = gate * 1024 + (rt * 2 + blkLoc) * 8 + u;   // source column
    lds[r][blkLoc * 32 + u * 4 + gate] = src[(size_t)(kt * 64 + r) * G4_ + g];
  }
  __syncthreads();
#pragma unroll
  for (int ii = 0; ii < 16; ++ii) {
    int idx = ii * 256 + tid;
    int rw = idx >> 6, cw = idx & 63;
    dst[(size_t)(rt * 64 + rw) * H_ + kt * 64 + cw] = f2bf(lds[cw][rw]);
  }
}

// -------- GEMM: C(bf16,[8192][4096],cols permuted) = A(f32,[8192][1024]) * Bt^T + bias --------
// Bt is [4096][1024] bf16 with rows already permuted (WxT). 128x128 tile, BK=64, 4 waves 2x2.
__global__ __launch_bounds__(256, 2) void gemm_xproj(
    const float* __restrict__ A, const u16* __restrict__ Bt,
    const float* __restrict__ bias, u16* __restrict__ C) {
  __shared__ __align__(16) u16 As[128 * 64];
  __shared__ __align__(16) u16 Bs[128 * 64];
  const int bid = blockIdx.x, tid = threadIdx.x;
  const int bn = bid & 31, bm = bid >> 5;
  const int lane = tid & 63, wid = tid >> 6;
  const int wm = wid >> 1, wn = wid & 1;
  const int l15 = lane & 15, lq = lane >> 4;
  const int srow = tid >> 2, qd = tid & 3;

  f32x4 acc[4][4];
#pragma unroll
  for (int i = 0; i < 4; ++i)
#pragma unroll
    for (int j = 0; j < 4; ++j) acc[i][j] = (f32x4){0.f, 0.f, 0.f, 0.f};

  const u32 rsw = (u32)((l15 & 7) << 4);

  for (int kt = 0; kt < 16; ++kt) {
    f32x4 av[2][4];
    u32x4 bv[2][2];
#pragma unroll
    for (int rr = 0; rr < 2; ++rr) {
      int row = rr * 64 + srow;
      const f32x4* ap = (const f32x4*)(A + (size_t)(bm * 128 + row) * 1024 + kt * 64 + qd * 16);
#pragma unroll
      for (int i = 0; i < 4; ++i) av[rr][i] = ap[i];
      const u32x4* bp = (const u32x4*)(Bt + (size_t)(bn * 128 + row) * 1024 + kt * 64 + qd * 16);
      bv[rr][0] = bp[0]; bv[rr][1] = bp[1];
    }
    __syncthreads();  // previous compute done before overwrite
#pragma unroll
    for (int rr = 0; rr < 2; ++rr) {
      int row = rr * 64 + srow;
      u32 sw = (u32)((row & 7) << 4);
      int base = row * 128 + qd * 32;
      u32x4 w0, w1;
      w0[0] = pk2(av[rr][0][0], av[rr][0][1]); w0[1] = pk2(av[rr][0][2], av[rr][0][3]);
      w0[2] = pk2(av[rr][1][0], av[rr][1][1]); w0[3] = pk2(av[rr][1][2], av[rr][1][3]);
      w1[0] = pk2(av[rr][2][0], av[rr][2][1]); w1[1] = pk2(av[rr][2][2], av[rr][2][3]);
      w1[2] = pk2(av[rr][3][0], av[rr][3][1]); w1[3] = pk2(av[rr][3][2], av[rr][3][3]);
      *(u32x4*)((char*)As + ((base) ^ sw)) = w0;
      *(u32x4*)((char*)As + ((base + 16) ^ sw)) = w1;
      *(u32x4*)((char*)Bs + ((base) ^ sw)) = bv[rr][0];
      *(u32x4*)((char*)Bs + ((base + 16) ^ sw)) = bv[rr][1];
    }
    __syncthreads();
#pragma unroll
    for (int k2 = 0; k2 < 2; ++k2) {
      short8 af[4], bf[4];
#pragma unroll
      for (int f = 0; f < 4; ++f) {
        af[f] = *(const short8*)((const char*)As +
                 (((wm * 64 + f * 16 + l15) * 128 + k2 * 64 + lq * 16) ^ rsw));
        bf[f] = *(const short8*)((const char*)Bs +
                 (((wn * 64 + f * 16 + l15) * 128 + k2 * 64 + lq * 16) ^ rsw));
      }
#pragma unroll
      for (int fi = 0; fi < 4; ++fi)
#pragma unroll
        for (int fj = 0; fj < 4; ++fj)
          acc[fi][fj] = MFMA16(af[fi], bf[fj], acc[fi][fj]);
    }
  }
  // epilogue: +bias (bias indexed in original g-space), store bf16
#pragma unroll
  for (int fj = 0; fj < 4; ++fj) {
    int gc = bn * 128 + wn * 64 + fj * 16 + l15;
    float bvv = bias[permcol(gc)];
#pragma unroll
    for (int fi = 0; fi < 4; ++fi) {
      int gr0 = bm * 128 + wm * 64 + fi * 16 + lq * 4;
#pragma unroll
      for (int r = 0; r < 4; ++r)
        C[(size_t)(gr0 + r) * 4096 + gc] = f2bf(acc[fi][fj][r] + bvv);
    }
  }
}

// -------- persistent LSTM scan: 128 blocks x 256 thr, 8 units/block --------
// hpub: 2 parity slots x 64KB, layout [k>>3][b][8] bf16. flags[blk] = steps published.
__global__ __launch_bounds__(256, 1) void lstm_scan(
    const u16* __restrict__ xproj, const u16* __restrict__ WhT,
    const int* __restrict__ lengths, u64* hpub, int* flags,
    float* __restrict__ outp, float* __restrict__ csf, float* __restrict__ hsf) {
  __shared__ f32x4 partv[16 * 64];                 // [w*4+qt][lane] 16KB
  __shared__ __align__(16) float out_stage[256];   // [b][u]
  __shared__ __align__(16) u16 h_stage[256];       // [b][u]
  const int blk = blockIdx.x, tid = threadIdx.x;
  const int lane = tid & 63, w = tid >> 6;
  const int l15 = lane & 15, q = lane >> 4;
  const int b = (w & 1) * 16 + l15;
  const int u_local = (w >> 1) * 4 + q;  // 0..7
  const int u_glob = blk * 8 + u_local;
  const int len = lengths[b];

  // Wh A-fragments live in registers for the whole scan (16 x short8)
  short8 afr[2][8];
#pragma unroll
  for (int tt = 0; tt < 2; ++tt)
#pragma unroll
    for (int ks = 0; ks < 8; ++ks)
      afr[tt][ks] = *(const short8*)(WhT + (size_t)(blk * 32 + tt * 16 + l15) * 1024 +
                                     w * 256 + ks * 32 + q * 8);

  f32x4 acc[2][2];
#pragma unroll
  for (int tt = 0; tt < 2; ++tt)
#pragma unroll
    for (int bc = 0; bc < 2; ++bc) acc[tt][bc] = (f32x4){0.f, 0.f, 0.f, 0.f};
  float c = 0.f, h = 0.f;

  for (int t = 0; t < 256; ++t) {
    u64 xp = *(const u64*)(xproj + (size_t)(b * 256 + t) * 4096 + blk * 32 + u_local * 4);
    if (t > 0) {
      // wait for the 32 producers of this wave's K-slice (full-flag coverage across waves)
      int fidx = w * 32 + (lane & 31);
      while (__hip_atomic_load(&flags[fidx], __ATOMIC_RELAXED, __HIP_MEMORY_SCOPE_AGENT) < t)
        __builtin_amdgcn_s_sleep(1);
      asm volatile("" ::: "memory");
      const char* hp = (const char*)(hpub + (size_t)((t - 1) & 1) * 8192);
      short8 bfv[16];
#pragma unroll
      for (int i = 0; i < 16; ++i) {
        const int ks = i >> 1, bc = i & 1;
        const char* p = hp + (((w * 32 + ks * 4 + q) * 32 + bc * 16 + l15) << 4);
        asm volatile("global_load_dwordx4 %0, %1, off sc0 sc1"
                     : "=v"(bfv[i]) : "v"(p) : "memory");
      }
      asm volatile("s_waitcnt vmcnt(0)" ::: "memory");
      __builtin_amdgcn_sched_barrier(0);
#pragma unroll
      for (int i = 0; i < 16; ++i) {
        const int ks = i >> 1, bc = i & 1;
        acc[0][bc] = MFMA16(afr[0][ks], bfv[i], acc[0][bc]);
        acc[1][bc] = MFMA16(afr[1][ks], bfv[i], acc[1][bc]);
      }
    }
    // cross-wave K reduction via LDS
#pragma unroll
    for (int tt = 0; tt < 2; ++tt)
#pragma unroll
      for (int bc = 0; bc < 2; ++bc)
        partv[(w * 4 + tt * 2 + bc) * 64 + lane] = acc[tt][bc];
    __syncthreads();  // B1
    f32x4 s = (f32x4){0.f, 0.f, 0.f, 0.f};
    if (t > 0) {
#pragma unroll
      for (int w2 = 0; w2 < 4; ++w2) s += partv[(w2 * 4 + w) * 64 + lane];
    }
    float zi = s[0] + bf2f((u16)(xp & 0xffffu));
    float zj = s[1] + bf2f((u16)((xp >> 16) & 0xffffu));
    float zf = s[2] + bf2f((u16)((xp >> 32) & 0xffffu)) + 1.f;  // FORGET_BIAS
    float zo = s[3] + bf2f((u16)(xp >> 48));
    float cn = sigm(zf) * c + sigm(zi) * tanh_(zj);
    float hn = sigm(zo) * tanh_(cn);
    bool mk = t < len;
    c = mk ? cn : c;
    h = mk ? hn : h;
    out_stage[b * 8 + u_local] = mk ? hn : 0.f;
    h_stage[b * 8 + u_local] = f2bf(h);
#pragma unroll
    for (int tt = 0; tt < 2; ++tt)
#pragma unroll
      for (int bc = 0; bc < 2; ++bc) acc[tt][bc] = (f32x4){0.f, 0.f, 0.f, 0.f};
    __syncthreads();  // B2 (drains vmcnt/lgkmcnt per wave)
    if (tid < 32) {   // coalesced publish: 32 lanes x 16B = this block's h chunk
      const u64* hsrc = (const u64*)h_stage;
      u64 v0 = hsrc[tid * 2], v1 = hsrc[tid * 2 + 1];
      u64* dstp = hpub + (size_t)(t & 1) * 8192 + (blk * 32 + tid) * 2;
      __hip_atomic_store(dstp, v0, __ATOMIC_RELAXED, __HIP_MEMORY_SCOPE_AGENT);
      __hip_atomic_store(dstp + 1, v1, __ATOMIC_RELAXED, __HIP_MEMORY_SCOPE_AGENT);
    }
    asm volatile("s_waitcnt vmcnt(0)" ::: "memory");  // h visible before flag
    if (tid == 0)
      __hip_atomic_store(&flags[blk], t + 1, __ATOMIC_RELAXED, __HIP_MEMORY_SCOPE_AGENT);
    if (tid < 32) {   // coalesced per-step output store
      const f32x4* osrc = (const f32x4*)out_stage;
      f32x4 o0 = osrc[tid * 2], o1 = osrc[tid * 2 + 1];
      f32x4* od = (f32x4*)(outp + (size_t)(tid * 256 + t) * 1024 + blk * 8);
      od[0] = o0; od[1] = o1;
    }
  }
  csf[b * 1024 + u_glob] = c;
  hsf[b * 1024 + u_glob] = h;
}

// -------- host launch --------
#define WS_XPROJ 0u
#define WS_WXT (64u << 20)
#define WS_WHT (80u << 20)
#define WS_HPUB (96u << 20)
#define WS_FLAGS ((96u << 20) + (512u << 10))

extern "C" void kernel_launch(void* const* d_in, const int* in_sizes, int n_in,
                              void* d_out, int out_size, void* d_ws, size_t ws_size,
                              hipStream_t stream) {
  const float* x = (const float*)d_in[0];
  const int* lengths = (const int*)d_in[1];
  const float* Wx = (const float*)d_in[2];
  const float* Wh = (const float*)d_in[3];
  const float* bias = (const float*)d_in[4];
  float* outp = (float*)d_out;

  if (ws_size < (size_t)WS_FLAGS + 4096) return;  // fail loudly (output stays poison)

  char* ws = (char*)d_ws;
  u16* xproj = (u16*)(ws + WS_XPROJ);
  u16* WxT = (u16*)(ws + WS_WXT);
  u16* WhT = (u16*)(ws + WS_WHT);
  u64* hpub = (u64*)(ws + WS_HPUB);     // per layer: 16384 u64 (2 parity slots)
  int* flags = (int*)(ws + WS_FLAGS);   // per layer: 128 ints

  hipMemsetAsync(flags, 0, 2 * 128 * sizeof(int), stream);
  transpose_convert<<<4096, 256, 0, stream>>>(Wx, Wh, WxT, WhT);

  float* cs = outp + RN_;
  float* hs = cs + 65536;

  // layer 0
  gemm_xproj<<<2048, 256, 0, stream>>>(x, WxT, bias, xproj);
  lstm_scan<<<128, 256, 0, stream>>>(xproj, WhT, lengths, hpub, flags, outp, cs, hs);
  // layer 1 (A = layer-0 output living in d_out's rnnout region)
  gemm_xproj<<<2048, 256, 0, stream>>>(outp, WxT + (size_t)4096 * 1024, bias + 4096, xproj);
  lstm_scan<<<128, 256, 0, stream>>>(xproj, WhT + (size_t)4096 * 1024, lengths,
                                     hpub + 16384, flags + 128, outp,
                                     cs + 32768, hs + 32768);
}

// Round 2
// 2524.703 us; speedup vs baseline: 1.0196x; 1.0196x over previous
//
#include <hip/hip_runtime.h>

typedef unsigned short u16;
typedef unsigned int u32;
typedef unsigned long long u64;
typedef __attribute__((ext_vector_type(8))) short short8;
typedef __attribute__((ext_vector_type(4))) float f32x4;
typedef __attribute__((ext_vector_type(4))) u32 u32x4;

#define RN_ 8388608  // B*T*H
#define MFMA16(a, b, c) __builtin_amdgcn_mfma_f32_16x16x32_bf16(a, b, c, 0, 0, 0)

__device__ __forceinline__ u16 f2bf(float f) {
  union { float f; u32 u; } v; v.f = f;
  u32 r = v.u + 0x7fffu + ((v.u >> 16) & 1u);  // RNE (inputs finite)
  return (u16)(r >> 16);
}
__device__ __forceinline__ float bf2f(u16 h) {
  union { u32 u; float f; } v; v.u = ((u32)h) << 16;
  return v.f;
}
__device__ __forceinline__ u32 pk2(float a, float b) {
  return (u32)f2bf(a) | ((u32)f2bf(b) << 16);
}
// scan column ordering: R = blk*32 + u_local*4 + gate  ->  original g = gate*1024 + blk*8 + u_local
__device__ __forceinline__ int permcol(int R) {
  return (R & 3) * 1024 + ((R >> 5) << 3) + ((R >> 2) & 7);
}
__device__ __forceinline__ float sigm(float x) { return 1.f / (1.f + __expf(-x)); }
__device__ __forceinline__ float tanh_(float x) {
  float e = __expf(2.f * x);
  return 1.f - 2.f / (e + 1.f);
}

// -------- transpose + convert + permute --------
// sel0: Wx l0 -> WxT1 [4096][1024]        (GEMM-1 B operand)
// sel1: Wx l1 -> WcT2 [4096][2048] cols 0..1023
// sel2: Wh l0 -> WhT1 [4096][1024]        (L1 scan weights)
// sel3: Wh l1 -> WcT2 cols 1024..2047    (L2 scan combined weights)
__global__ __launch_bounds__(256) void transpose_convert(
    const float* __restrict__ Wx, const float* __restrict__ Wh,
    u16* __restrict__ WxT1, u16* __restrict__ WhT1, u16* __restrict__ WcT2) {
  __shared__ float lds[64][65];
  const int bid = blockIdx.x, tid = threadIdx.x;
  const int sel = bid >> 10;
  const int tile = bid & 1023;
  const int kt = tile & 15, rt = tile >> 4;  // 16 k-tiles x 64 R-tiles
  const float* src;
  u16* dst;
  int rstride, coff;
  if (sel == 0)      { src = Wx;                              dst = WxT1; rstride = 1024; coff = 0; }
  else if (sel == 1) { src = Wx + (size_t)1024 * 4096;        dst = WcT2; rstride = 2048; coff = 0; }
  else if (sel == 2) { src = Wh;                              dst = WhT1; rstride = 1024; coff = 0; }
  else               { src = Wh + (size_t)1024 * 4096;        dst = WcT2; rstride = 2048; coff = 1024; }
#pragma unroll
  for (int ii = 0; ii < 16; ++ii) {
    int idx = ii * 256 + tid;
    int r = idx >> 6, c = idx & 63;
    int run = c >> 3, u = c & 7;
    int blkLoc = run >> 2, gate = run & 3;
    int g = gate * 1024 + (rt * 2 + blkLoc) * 8 + u;
    lds[r][blkLoc * 32 + u * 4 + gate] = src[(size_t)(kt * 64 + r) * 4096 + g];
  }
  __syncthreads();
#pragma unroll
  for (int ii = 0; ii < 16; ++ii) {
    int idx = ii * 256 + tid;
    int rw = idx >> 6, cw = idx & 63;
    dst[(size_t)(rt * 64 + rw) * rstride + coff + kt * 64 + cw] = f2bf(lds[cw][rw]);
  }
}

// -------- GEMM: xproj(bf16,[8192][4096],cols permuted) = x * WxT1^T + bias --------
__global__ __launch_bounds__(256, 2) void gemm_xproj(
    const float* __restrict__ A, const u16* __restrict__ Bt,
    const float* __restrict__ bias, u16* __restrict__ C) {
  __shared__ __align__(16) u16 As[128 * 64];
  __shared__ __align__(16) u16 Bs[128 * 64];
  const int bid = blockIdx.x, tid = threadIdx.x;
  const int bn = bid & 31, bm = bid >> 5;
  const int lane = tid & 63, wid = tid >> 6;
  const int wm = wid >> 1, wn = wid & 1;
  const int l15 = lane & 15, lq = lane >> 4;
  const int srow = tid >> 2, qd = tid & 3;

  f32x4 acc[4][4];
#pragma unroll
  for (int i = 0; i < 4; ++i)
#pragma unroll
    for (int j = 0; j < 4; ++j) acc[i][j] = (f32x4){0.f, 0.f, 0.f, 0.f};

  const u32 rsw = (u32)((l15 & 7) << 4);

  for (int kt = 0; kt < 16; ++kt) {
    f32x4 av[2][4];
    u32x4 bv[2][2];
#pragma unroll
    for (int rr = 0; rr < 2; ++rr) {
      int row = rr * 64 + srow;
      const f32x4* ap = (const f32x4*)(A + (size_t)(bm * 128 + row) * 1024 + kt * 64 + qd * 16);
#pragma unroll
      for (int i = 0; i < 4; ++i) av[rr][i] = ap[i];
      const u32x4* bp = (const u32x4*)(Bt + (size_t)(bn * 128 + row) * 1024 + kt * 64 + qd * 16);
      bv[rr][0] = bp[0]; bv[rr][1] = bp[1];
    }
    __syncthreads();
#pragma unroll
    for (int rr = 0; rr < 2; ++rr) {
      int row = rr * 64 + srow;
      u32 sw = (u32)((row & 7) << 4);
      int base = row * 128 + qd * 32;
      u32x4 w0, w1;
      w0[0] = pk2(av[rr][0][0], av[rr][0][1]); w0[1] = pk2(av[rr][0][2], av[rr][0][3]);
      w0[2] = pk2(av[rr][1][0], av[rr][1][1]); w0[3] = pk2(av[rr][1][2], av[rr][1][3]);
      w1[0] = pk2(av[rr][2][0], av[rr][2][1]); w1[1] = pk2(av[rr][2][2], av[rr][2][3]);
      w1[2] = pk2(av[rr][3][0], av[rr][3][1]); w1[3] = pk2(av[rr][3][2], av[rr][3][3]);
      *(u32x4*)((char*)As + ((base) ^ sw)) = w0;
      *(u32x4*)((char*)As + ((base + 16) ^ sw)) = w1;
      *(u32x4*)((char*)Bs + ((base) ^ sw)) = bv[rr][0];
      *(u32x4*)((char*)Bs + ((base + 16) ^ sw)) = bv[rr][1];
    }
    __syncthreads();
#pragma unroll
    for (int k2 = 0; k2 < 2; ++k2) {
      short8 af[4], bf[4];
#pragma unroll
      for (int f = 0; f < 4; ++f) {
        af[f] = *(const short8*)((const char*)As +
                 (((wm * 64 + f * 16 + l15) * 128 + k2 * 64 + lq * 16) ^ rsw));
        bf[f] = *(const short8*)((const char*)Bs +
                 (((wn * 64 + f * 16 + l15) * 128 + k2 * 64 + lq * 16) ^ rsw));
      }
#pragma unroll
      for (int fi = 0; fi < 4; ++fi)
#pragma unroll
        for (int fj = 0; fj < 4; ++fj)
          acc[fi][fj] = MFMA16(af[fi], bf[fj], acc[fi][fj]);
    }
  }
#pragma unroll
  for (int fj = 0; fj < 4; ++fj) {
    int gc = bn * 128 + wn * 64 + fj * 16 + l15;
    float bvv = bias[permcol(gc)];
#pragma unroll
    for (int fi = 0; fi < 4; ++fi) {
      int gr0 = bm * 128 + wm * 64 + fi * 16 + lq * 4;
#pragma unroll
      for (int r = 0; r < 4; ++r)
        C[(size_t)(gr0 + r) * 4096 + gc] = f2bf(acc[fi][fj][r] + bvv);
    }
  }
}

// -------- fused 2-layer persistent scan --------
// 256 blocks: blk<128 = layer1 (K=1024, weights WhT1), blk>=128 = layer2
// (K=2048 combined [Wx2;Wh2] against [out1(t); h2(t-1)]).
// hpub1: 4 slots x 64KB (t&3); hpub2: 2 slots x 64KB (t&1). Layout [k>>3][b] x 16B.
// flags[0..127]=L1 steps published, flags[128..255]=L2.
// All published h values are MASKED (mask ? h_new : 0): frozen batches ignore z,
// and layer2's input needs exactly the masked value.
template <int LAYER>
__device__ __forceinline__ void scan_body(
    f32x4* partv, float* out_stage, u16* h_stage, int blk2,
    const u16* __restrict__ xproj, const u16* __restrict__ Wt,
    const float* __restrict__ bias2, const int* __restrict__ lengths,
    u64* hpub1, u64* hpub2, int* flags,
    float* __restrict__ outp, float* __restrict__ csf, float* __restrict__ hsf) {
  const int tid = threadIdx.x;
  const int lane = tid & 63, w = tid >> 6;
  const int l15 = lane & 15, q = lane >> 4;
  const int b = (w & 1) * 16 + l15;
  const int u_local = (w >> 1) * 4 + q;
  const int len = lengths[b];

  constexpr int NKS = LAYER ? 16 : 8;
  constexpr int KSTRIDE = LAYER ? 2048 : 1024;
  const int wk = w * (LAYER ? 512 : 256);

  short8 afr[2][NKS];
#pragma unroll
  for (int tt = 0; tt < 2; ++tt)
#pragma unroll
    for (int ks = 0; ks < NKS; ++ks)
      afr[tt][ks] = *(const short8*)(Wt + (size_t)(blk2 * 32 + tt * 16 + l15) * KSTRIDE +
                                     wk + ks * 32 + q * 8);

  float bg0 = 0.f, bg1 = 0.f, bg2 = 0.f, bg3 = 0.f;
  if (LAYER) {
    bg0 = bias2[permcol(blk2 * 32 + u_local * 4 + 0)];
    bg1 = bias2[permcol(blk2 * 32 + u_local * 4 + 1)];
    bg2 = bias2[permcol(blk2 * 32 + u_local * 4 + 2)];
    bg3 = bias2[permcol(blk2 * 32 + u_local * 4 + 3)];
  }

  f32x4 acc[2][2];
#pragma unroll
  for (int tt = 0; tt < 2; ++tt)
#pragma unroll
    for (int bc = 0; bc < 2; ++bc) acc[tt][bc] = (f32x4){0.f, 0.f, 0.f, 0.f};
  float c = 0.f, h = 0.f;

  for (int t = 0; t < 256; ++t) {
    u64 xp = 0;
    if (!LAYER)
      xp = *(const u64*)(xproj + ((size_t)b * 256 + t) * 4096 + blk2 * 32 + u_local * 4);

    // ---- wave0 polls all 256 flags; one barrier releases the block ----
    if (w == 0) {
      const int n1 = LAYER ? t + 1 : t;       // flag1 threshold
      const int n2 = LAYER ? t : t - 3;       // flag2 threshold (slot reuse / h2 avail)
      if (n1 > 0 || n2 > 0) {
        const int thr = (lane < 32) ? n1 : n2;
        const u32x4* fp = (const u32x4*)flags + lane;
        while (1) {
          u32x4 fv;
          asm volatile("global_load_dwordx4 %0, %1, off sc0 sc1"
                       : "=v"(fv) : "v"(fp) : "memory");
          asm volatile("s_waitcnt vmcnt(0)" ::: "memory");
          bool ok = (int)fv[0] >= thr && (int)fv[1] >= thr &&
                    (int)fv[2] >= thr && (int)fv[3] >= thr;
          if (__all(ok)) break;
          __builtin_amdgcn_s_sleep(2);
        }
      }
    }
    __syncthreads();  // BP: flags satisfied for whole block

    // ---- load h fragments, MFMA ----
    if (!LAYER) {
      if (t > 0) {
        const char* hp = (const char*)(hpub1 + (size_t)((t - 1) & 3) * 8192);
        short8 bfv[16];
#pragma unroll
        for (int i = 0; i < 16; ++i) {
          const int ks = i >> 1, bc = i & 1;
          const char* p = hp + (((w * 32 + ks * 4 + q) * 32 + bc * 16 + l15) << 4);
          asm volatile("global_load_dwordx4 %0, %1, off sc0 sc1"
                       : "=v"(bfv[i]) : "v"(p) : "memory");
        }
        asm volatile("s_waitcnt vmcnt(0)" ::: "memory");
        __builtin_amdgcn_sched_barrier(0);
#pragma unroll
        for (int i = 0; i < 16; ++i) {
          const int ks = i >> 1, bc = i & 1;
          acc[0][bc] = MFMA16(afr[0][ks], bfv[i], acc[0][bc]);
          acc[1][bc] = MFMA16(afr[1][ks], bfv[i], acc[1][bc]);
        }
      }
    } else {
      const char* hp;
      int kb;
      if (w < 2) { hp = (const char*)(hpub1 + (size_t)(t & 3) * 8192); kb = w * 64; }
      else       { hp = (const char*)(hpub2 + (size_t)((t - 1) & 1) * 8192); kb = (w - 2) * 64; }
      if (w < 2 || t > 0) {
#pragma unroll
        for (int g = 0; g < 2; ++g) {   // 2 groups of 16 frags (VGPR cap)
          short8 bfv[16];
#pragma unroll
          for (int i = 0; i < 16; ++i) {
            const int ks = g * 8 + (i >> 1), bc = i & 1;
            const char* p = hp + (((kb + ks * 4 + q) * 32 + bc * 16 + l15) << 4);
            asm volatile("global_load_dwordx4 %0, %1, off sc0 sc1"
                         : "=v"(bfv[i]) : "v"(p) : "memory");
          }
          asm volatile("s_waitcnt vmcnt(0)" ::: "memory");
          __builtin_amdgcn_sched_barrier(0);
#pragma unroll
          for (int i = 0; i < 16; ++i) {
            const int ks = g * 8 + (i >> 1), bc = i & 1;
            acc[0][bc] = MFMA16(afr[0][ks], bfv[i], acc[0][bc]);
            acc[1][bc] = MFMA16(afr[1][ks], bfv[i], acc[1][bc]);
          }
        }
      }
    }

    // ---- cross-wave K reduction ----
#pragma unroll
    for (int tt = 0; tt < 2; ++tt)
#pragma unroll
      for (int bc = 0; bc < 2; ++bc) {
        partv[(w * 4 + tt * 2 + bc) * 64 + lane] = acc[tt][bc];
        acc[tt][bc] = (f32x4){0.f, 0.f, 0.f, 0.f};
      }
    __syncthreads();  // B1
    f32x4 s = (f32x4){0.f, 0.f, 0.f, 0.f};
#pragma unroll
    for (int w2 = 0; w2 < 4; ++w2) s += partv[(w2 * 4 + w) * 64 + lane];

    float zi, zj, zf, zo;
    if (!LAYER) {
      zi = s[0] + bf2f((u16)(xp & 0xffffu));
      zj = s[1] + bf2f((u16)((xp >> 16) & 0xffffu));
      zf = s[2] + bf2f((u16)((xp >> 32) & 0xffffu)) + 1.f;
      zo = s[3] + bf2f((u16)(xp >> 48));
    } else {
      zi = s[0] + bg0;
      zj = s[1] + bg1;
      zf = s[2] + bg2 + 1.f;
      zo = s[3] + bg3;
    }
    float cn = sigm(zf) * c + sigm(zi) * tanh_(zj);
    float hn = sigm(zo) * tanh_(cn);
    bool mk = t < len;
    c = mk ? cn : c;
    h = mk ? hn : h;
    float ov = mk ? hn : 0.f;
    h_stage[b * 8 + u_local] = f2bf(ov);
    if (LAYER) out_stage[b * 8 + u_local] = ov;
    __syncthreads();  // B2

    // ---- publish h + flag ----
    if (tid < 32) {
      u64* hd = LAYER ? (hpub2 + (size_t)(t & 1) * 8192)
                      : (hpub1 + (size_t)(t & 3) * 8192);
      const u64* hsrc = (const u64*)h_stage;
      u64 v0 = hsrc[tid * 2], v1 = hsrc[tid * 2 + 1];
      __hip_atomic_store(hd + (blk2 * 32 + tid) * 2, v0, __ATOMIC_RELAXED,
                         __HIP_MEMORY_SCOPE_AGENT);
      __hip_atomic_store(hd + (blk2 * 32 + tid) * 2 + 1, v1, __ATOMIC_RELAXED,
                         __HIP_MEMORY_SCOPE_AGENT);
    }
    asm volatile("s_waitcnt vmcnt(0)" ::: "memory");  // h visible before flag
    if (tid == 0)
      __hip_atomic_store(flags + LAYER * 128 + blk2, t + 1, __ATOMIC_RELAXED,
                         __HIP_MEMORY_SCOPE_AGENT);
    if (LAYER && tid < 32) {  // per-step rnnout store (layer-2 only)
      const f32x4* osrc = (const f32x4*)out_stage;
      f32x4 o0 = osrc[tid * 2], o1 = osrc[tid * 2 + 1];
      f32x4* od = (f32x4*)(outp + ((size_t)tid * 256 + t) * 1024 + blk2 * 8);
      od[0] = o0; od[1] = o1;
    }
  }
  csf[LAYER * 32768 + b * 1024 + blk2 * 8 + u_local] = c;
  hsf[LAYER * 32768 + b * 1024 + blk2 * 8 + u_local] = h;
}

__global__ __launch_bounds__(256, 2) void lstm_fused(
    const u16* __restrict__ xproj, const u16* __restrict__ WhT1,
    const u16* __restrict__ WcT2, const float* __restrict__ bias2,
    const int* __restrict__ lengths, u64* hpub1, u64* hpub2, int* flags,
    float* __restrict__ outp, float* __restrict__ csf, float* __restrict__ hsf) {
  __shared__ f32x4 partv[16 * 64];
  __shared__ __align__(16) float out_stage[256];
  __shared__ __align__(16) u16 h_stage[256];
  const int blk = blockIdx.x;
  if (blk < 128)
    scan_body<0>(partv, out_stage, h_stage, blk, xproj, WhT1, bias2, lengths,
                 hpub1, hpub2, flags, outp, csf, hsf);
  else
    scan_body<1>(partv, out_stage, h_stage, blk - 128, xproj, WcT2, bias2, lengths,
                 hpub1, hpub2, flags, outp, csf, hsf);
}

// -------- workspace layout --------
#define WS_XPROJ 0u
#define WS_WXT1 (64u << 20)
#define WS_WHT1 (72u << 20)
#define WS_WCT2 (80u << 20)
#define WS_HPUB1 (96u << 20)                       // 4 x 64KB
#define WS_HPUB2 ((96u << 20) + (256u << 10))      // 2 x 64KB
#define WS_FLAGS ((96u << 20) + (384u << 10))      // 256 ints

extern "C" void kernel_launch(void* const* d_in, const int* in_sizes, int n_in,
                              void* d_out, int out_size, void* d_ws, size_t ws_size,
                              hipStream_t stream) {
  const float* x = (const float*)d_in[0];
  const int* lengths = (const int*)d_in[1];
  const float* Wx = (const float*)d_in[2];
  const float* Wh = (const float*)d_in[3];
  const float* bias = (const float*)d_in[4];
  float* outp = (float*)d_out;

  if (ws_size < (size_t)WS_FLAGS + 4096) return;  // fail loudly (output stays poison)

  char* ws = (char*)d_ws;
  u16* xproj = (u16*)(ws + WS_XPROJ);
  u16* WxT1 = (u16*)(ws + WS_WXT1);
  u16* WhT1 = (u16*)(ws + WS_WHT1);
  u16* WcT2 = (u16*)(ws + WS_WCT2);
  u64* hpub1 = (u64*)(ws + WS_HPUB1);
  u64* hpub2 = (u64*)(ws + WS_HPUB2);
  int* flags = (int*)(ws + WS_FLAGS);

  hipMemsetAsync(flags, 0, 256 * sizeof(int), stream);
  transpose_convert<<<4096, 256, 0, stream>>>(Wx, Wh, WxT1, WhT1, WcT2);

  float* cs = outp + RN_;
  float* hs = cs + 65536;

  gemm_xproj<<<2048, 256, 0, stream>>>(x, WxT1, bias, xproj);
  lstm_fused<<<256, 256, 0, stream>>>(xproj, WhT1, WcT2, bias + 4096, lengths,
                                      hpub1, hpub2, flags, outp, cs, hs);
}